// Round 12
// baseline (4064.743 us; speedup 1.0000x reference)
//
#include <hip/hip_runtime.h>
#include <hip/hip_bf16.h>
#include <stdint.h>

typedef __bf16 bf16x8 __attribute__((ext_vector_type(8)));
typedef float f32x4 __attribute__((ext_vector_type(4)));
typedef short short8 __attribute__((ext_vector_type(8)));
typedef unsigned long long u64;
typedef unsigned int u32;

#define B_ 32
#define T_ 512
#define D_ 1024
#define NG 4096
#define L_ 3
#define HD 32            // rotating h step-buffer depth
#define HSLOT 32768      // ushorts per slot (32 batches x 1024 units)
#define NWG3 192
#define SLK 12           // pipeline-fill slack (steps of upstream lead)
#define BP_ 20           // backpressure window (max lead 20+8=28 < HD)

__device__ inline unsigned short f2bf(float f) {
  unsigned u = __float_as_uint(f);
  unsigned r = (u + 0x7fffu + ((u >> 16) & 1u)) >> 16;
  return (unsigned short)r;
}
__device__ inline float bf2f(unsigned short h) {
  return __uint_as_float(((unsigned)h) << 16);
}
__device__ __forceinline__ float sigm(float x) { return 1.f / (1.f + __expf(-x)); }
__device__ __forceinline__ float tanh_(float x) {
  float e2 = __expf(-2.f * fabsf(x));
  return copysignf((1.f - e2) / (1.f + e2), x);
}
__device__ __forceinline__ u32 ld_mall(const u32* p) {
  return __hip_atomic_load(p, __ATOMIC_RELAXED, __HIP_MEMORY_SCOPE_AGENT);
}

// ---------------- f32 -> bf16 convert (vectorized) ----------------
__global__ __launch_bounds__(256) void k_conv(const float* __restrict__ in,
                                              unsigned short* __restrict__ out, int n8) {
  int i = blockIdx.x * 256 + threadIdx.x;
  if (i >= n8) return;
  const float4* p = (const float4*)(in) + (size_t)i * 2;
  float4 a = p[0], b = p[1];
  short8 o;
  o[0] = (short)f2bf(a.x); o[1] = (short)f2bf(a.y); o[2] = (short)f2bf(a.z); o[3] = (short)f2bf(a.w);
  o[4] = (short)f2bf(b.x); o[5] = (short)f2bf(b.y); o[6] = (short)f2bf(b.z); o[7] = (short)f2bf(b.w);
  *((short8*)out + i) = o;
}

// ---------------- transpose+convert weights: (L,K,N) f32 -> (L,N,K) bf16 ----------------
__global__ __launch_bounds__(256) void k_transw(const float* __restrict__ in,
                                                unsigned short* __restrict__ out) {
  __shared__ float Tt[32][33];
  int k0 = blockIdx.x * 32, n0 = blockIdx.y * 32, l = blockIdx.z;
  const float* ip = in + (size_t)l * D_ * NG;
  unsigned short* op = out + (size_t)l * NG * D_;
  int r = threadIdx.x >> 5, c = threadIdx.x & 31;
  for (int rr = r; rr < 32; rr += 8)
    Tt[rr][c] = ip[(size_t)(k0 + rr) * NG + n0 + c];
  __syncthreads();
  for (int rr = r; rr < 32; rr += 8)
    op[(size_t)(n0 + rr) * D_ + k0 + c] = f2bf(Tt[c][rr]);
}

// ---------------- input-path GEMM (layer 0 only): Z = X @ Wi0 ----------------
#define PAD 40
__global__ __launch_bounds__(256) void k_gemm_in(const unsigned short* __restrict__ X,
                                                 const unsigned short* __restrict__ WT,
                                                 unsigned short* __restrict__ Z) {
  __shared__ short Al[128 * PAD];
  __shared__ short Bl[128 * PAD];
  int bx = blockIdx.x;
  int m0 = (bx >> 5) * 128, n0 = (bx & 31) * 128;
  int tid = threadIdx.x, lane = tid & 63, wv = tid >> 6;
  int wm = (wv >> 1) * 64, wn = (wv & 1) * 64;
  int l15 = lane & 15, lh = lane >> 4;
  f32x4 acc[4][4] = {};
  for (int s = 0; s < 32; ++s) {
    int k0 = s * 32;
    __syncthreads();
    for (int rr = 0; rr < 2; ++rr) {
      int ch = rr * 256 + tid;
      int row = ch >> 2, ko = (ch & 3) * 8;
      *(short8*)&Al[row * PAD + ko] = *(const short8*)&X[(size_t)(m0 + row) * 1024 + k0 + ko];
      *(short8*)&Bl[row * PAD + ko] = *(const short8*)&WT[(size_t)(n0 + row) * 1024 + k0 + ko];
    }
    __syncthreads();
    bf16x8 af[4], bfr[4];
    for (int mi = 0; mi < 4; ++mi)
      af[mi] = *(const bf16x8*)&Al[(wm + mi * 16 + l15) * PAD + lh * 8];
    for (int ni = 0; ni < 4; ++ni)
      bfr[ni] = *(const bf16x8*)&Bl[(wn + ni * 16 + l15) * PAD + lh * 8];
    for (int mi = 0; mi < 4; ++mi)
      for (int ni = 0; ni < 4; ++ni)
        acc[mi][ni] = __builtin_amdgcn_mfma_f32_16x16x32_bf16(af[mi], bfr[ni], acc[mi][ni], 0, 0, 0);
  }
  for (int mi = 0; mi < 4; ++mi)
    for (int ni = 0; ni < 4; ++ni)
      for (int r2 = 0; r2 < 4; ++r2) {
        int row = m0 + wm + mi * 16 + (lane >> 4) * 4 + r2;
        int col = n0 + wn + ni * 16 + l15;
        Z[(size_t)row * NG + col] = f2bf(acc[mi][ni][r2]);
      }
}

// ---------------- fused wavefronted 3-layer persistent recurrent kernel ----------------
// Round-12: round-7 skeleton (proven 3.54ms) + REAL cross-layer slack.
//  * One-time pipeline-fill lag: layer l waits until layer l-1 has finished SLK=12
//    steps before starting t=0. Equal mean periods then keep lead ~= 12 (bounded
//    random walk in [1, 28]) -> each layer's period is gated only by its OWN chain,
//    decoupled from upstream jitter. (Round-7/11 had lead=1: lockstep, jitter adds.)
//  * Steady-state upstream check stays >= t+1 (correctness), served from a wave-min
//    cache -> actual poll ~once per 12 steps.
//  * Backpressure: downstream >= t-20, checked every 8 steps (max lead 28 < HD=32).
//  * Fence every 32 own-steps (ring-reuse freshness, proven cadence).
//  * Single-wave (kw==0) polling + __syncthreads join, as round 7.
template<int LAY>
__device__ __forceinline__ void rec_body(
    const unsigned short* __restrict__ WiL, const unsigned short* __restrict__ WhL,
    const unsigned short* __restrict__ Zin0, const float* __restrict__ biasL,
    unsigned short* __restrict__ hh, unsigned int* __restrict__ flags,
    float* __restrict__ yout, float* __restrict__ hT, float* __restrict__ cT,
    int wgl, float* zsb) {
  int tid = threadIdx.x, lane = tid & 63, kw = tid >> 6;
  int l15 = lane & 15, lh = lane >> 4;
  int U = wgl * 16;
  constexpr int NKF = (LAY == 0) ? 4 : 8;   // K-frags per wave (kspan = NKF*32)

  // ---- load this wave's weight B-fragments (register-resident) ----
  bf16x8 bw[4 * NKF];
  {
    const unsigned short* Wsrc;
    int k0;
    if (LAY == 0) { Wsrc = WhL; k0 = kw * 128; }
    else { Wsrc = (kw < 4) ? WiL : WhL; k0 = (kw & 3) * 256; }
#pragma unroll
    for (int nt = 0; nt < 4; ++nt)
#pragma unroll
      for (int kf = 0; kf < NKF; ++kf)
        bw[nt * NKF + kf] =
            *(const bf16x8*)&Wsrc[(size_t)(nt * 1024 + U + l15) * 1024 + k0 + kf * 32 + lh * 8];
  }
#pragma unroll
  for (int i = 0; i < 4 * NKF; ++i) asm volatile("" : "+v"(bw[i]));

  // elementwise cell: thread -> (batch b, unit j)
  int b = tid >> 4, j = tid & 15;
  int u = U + j;
  float bz0 = biasL[u], bz1 = biasL[1024 + u], bz2 = biasL[2048 + u], bz3 = biasL[3072 + u];
  float cst = 0.f;
  unsigned short* hhme = hh + (size_t)LAY * HD * HSLOT;
  const unsigned short* hhin = (LAY == 0) ? hhme : hh + (size_t)(LAY - 1) * HD * HSLOT;
  u32 upc = 0;  // wave-min cache of upstream flags (wave kw==0 only)

  // ---- one-time pipeline-fill lag: upstream lead >= SLK before starting ----
  if (LAY > 0) {
    if (kw == 0) {
      const u32* fp = flags + (LAY - 1) * 64 + lane;
      u32 f;
      for (;;) {
        f = ld_mall(fp);
        if (__all((int)(f >= (u32)SLK))) break;
        __builtin_amdgcn_s_sleep(1);
      }
      u32 m = f;
#pragma unroll
      for (int o = 32; o >= 1; o >>= 1) {
        u32 x2 = (u32)__shfl_xor((int)m, o);
        m = m < x2 ? m : x2;
      }
      upc = m;
    }
    __syncthreads();
  }

  for (int t = 0; t < T_; ++t) {
    // ---- Zin0 prefetch (layer 0 only; overlaps polls) ----
    unsigned short zv0 = 0, zv1 = 0, zv2 = 0, zv3 = 0;
    if (LAY == 0) {
      const unsigned short* zr = Zin0 + (size_t)(b * T_ + t) * NG + u;
      zv0 = zr[0]; zv1 = zr[1024]; zv2 = zr[2048]; zv3 = zr[3072];
    }
    // ---- single-wave dependency polls + join (round-7 structure) ----
    if (kw == 0) {
      if (t > 0) {
        const u32* fp = flags + LAY * 64 + lane;
        for (;;) {
          u32 f = ld_mall(fp);
          if (__all((int)(f >= (u32)t))) break;
          __builtin_amdgcn_s_sleep(1);
        }
      }
      if (LAY > 0 && upc < (u32)(t + 1)) {
        const u32* fp = flags + (LAY - 1) * 64 + lane;
        u32 f;
        for (;;) {
          f = ld_mall(fp);
          if (__all((int)(f >= (u32)(t + 1)))) break;
          __builtin_amdgcn_s_sleep(1);
        }
        u32 m = f;
#pragma unroll
        for (int o = 32; o >= 1; o >>= 1) {
          u32 x2 = (u32)__shfl_xor((int)m, o);
          m = m < x2 ? m : x2;
        }
        upc = m;
      }
      if (LAY < 2 && t > 0 && (t & 7) == 0) {
        const u32* fd = flags + (LAY + 1) * 64 + lane;
        u32 need = (t > BP_) ? (u32)(t - BP_) : 0u;
        for (;;) {
          u32 f = ld_mall(fd);
          if (__all((int)(f >= need))) break;
          __builtin_amdgcn_s_sleep(1);
        }
      }
      if (t > 0 && (t & 31) == 0)
        __builtin_amdgcn_fence(__ATOMIC_ACQUIRE, "agent");  // ring-reuse freshness
    }
    __syncthreads();

    // ---- GEMM: this wave's K-slice (unconditional; slot HD-1 zeroed for t==0) ----
    {
      const unsigned short* hsrc;
      if (LAY == 0)      hsrc = hhme + (size_t)((t - 1) & (HD - 1)) * HSLOT;
      else if (kw < 4)   hsrc = hhin + (size_t)(t & (HD - 1)) * HSLOT;
      else               hsrc = hhme + (size_t)((t - 1) & (HD - 1)) * HSLOT;
      f32x4 acc[2][4] = {};
#pragma unroll
      for (int kf = 0; kf < NKF; ++kf) {
        int k = (LAY == 0 ? kw * 128 : (kw & 3) * 256) + kf * 32 + lh * 8;
        const unsigned short* pa = hsrc + (k >> 2) * 128;
        u64 x0 = *(const u64*)(pa + l15 * 4);
        u64 x1 = *(const u64*)(pa + 128 + l15 * 4);
        u64 x2 = *(const u64*)(pa + 64 + l15 * 4);
        u64 x3 = *(const u64*)(pa + 192 + l15 * 4);
        bf16x8 a0, a1;
        ((u64*)&a0)[0] = x0; ((u64*)&a0)[1] = x1;
        ((u64*)&a1)[0] = x2; ((u64*)&a1)[1] = x3;
#pragma unroll
        for (int nt = 0; nt < 4; ++nt) {
          acc[0][nt] = __builtin_amdgcn_mfma_f32_16x16x32_bf16(a0, bw[nt * NKF + kf], acc[0][nt], 0, 0, 0);
          acc[1][nt] = __builtin_amdgcn_mfma_f32_16x16x32_bf16(a1, bw[nt * NKF + kf], acc[1][nt], 0, 0, 0);
        }
      }
#pragma unroll
      for (int mt = 0; mt < 2; ++mt)
#pragma unroll
        for (int nt = 0; nt < 4; ++nt)
          *(f32x4*)&zsb[(((kw * 8) + mt * 4 + nt) * 64 + lane) * 4] = acc[mt][nt];
    }
    __syncthreads();   // sync_A: all partials in zsb

    // ---- reduce 8 partials + gates + state update ----
    float hv;
    {
      int mt = b >> 4, lzs = ((b & 15) >> 2) * 16 + j, r = b & 3;
      float z0 = bz0, z1 = bz1, z2 = bz2, z3 = bz3;
#pragma unroll
      for (int k2 = 0; k2 < 8; ++k2) {
        int base = ((k2 * 8 + mt * 4) * 64 + lzs) * 4 + r;
        z0 += zsb[base];
        z1 += zsb[base + 256];
        z2 += zsb[base + 512];
        z3 += zsb[base + 768];
      }
      if (LAY == 0) { z0 += bf2f(zv0); z1 += bf2f(zv1); z2 += bf2f(zv2); z3 += bf2f(zv3); }
      float ig = sigm(z0), fg = sigm(z1), gg = tanh_(z2), og = sigm(z3);
      cst = fg * cst + ig * gg;
      hv = og * tanh_(cst);
      unsigned short hw = f2bf(hv);
      unsigned short* ha = hhme + (size_t)(t & (HD - 1)) * HSLOT + (u >> 2) * 128 + b * 4 + (u & 3);
      unsigned hw32 = hw;
      asm volatile("global_store_short %0, %1, off sc0 sc1" :: "v"(ha), "v"(hw32) : "memory");
    }
    // drain h-stores only, then signal
    asm volatile("s_waitcnt vmcnt(0)" ::: "memory");
    __syncthreads();   // sync_B: h complete; also protects zsb reuse next step
    if (tid == 0)
      __hip_atomic_store(&flags[LAY * 64 + wgl], (u32)(t + 1), __ATOMIC_RELAXED,
                         __HIP_MEMORY_SCOPE_AGENT);
    // ---- off-critical-path output stores ----
    if (LAY == 2) __builtin_nontemporal_store(hv, &yout[(size_t)(b * T_ + t) * 1024 + u]);
    if (t == T_ - 1) {
      hT[LAY * (B_ * 1024) + b * 1024 + u] = hv;
      cT[LAY * (B_ * 1024) + b * 1024 + u] = cst;
    }
  }
}

__global__ __launch_bounds__(512)
__attribute__((amdgpu_waves_per_eu(2, 2)))
void k_rec3(
    const unsigned short* __restrict__ WiT, const unsigned short* __restrict__ WhT,
    const unsigned short* __restrict__ Zin0, const float* __restrict__ bias,
    unsigned short* __restrict__ hh, unsigned int* __restrict__ flags,
    float* __restrict__ yout, float* __restrict__ hT, float* __restrict__ cT) {
  extern __shared__ float zsb[];   // 64KB: [kw][8][64][4] f32
  int wg = blockIdx.x;
  int lay = (wg >= 64) + (wg >= 128);
  int wgl = wg & 63;
  const unsigned short* WiL = WiT + (size_t)lay * NG * 1024;
  const unsigned short* WhL = WhT + (size_t)lay * NG * 1024;
  const float* biasL = bias + lay * NG;
  if (lay == 0)      rec_body<0>(WiL, WhL, Zin0, biasL, hh, flags, yout, hT, cT, wgl, zsb);
  else if (lay == 1) rec_body<1>(WiL, WhL, Zin0, biasL, hh, flags, yout, hT, cT, wgl, zsb);
  else               rec_body<2>(WiL, WhL, Zin0, biasL, hh, flags, yout, hT, cT, wgl, zsb);
}

extern "C" void kernel_launch(void* const* d_in, const int* in_sizes, int n_in,
                              void* d_out, int out_size, void* d_ws, size_t ws_size,
                              hipStream_t stream) {
  const float* x = (const float*)d_in[0];
  const float* Wi = (const float*)d_in[1];
  const float* Wh = (const float*)d_in[2];
  const float* bias = (const float*)d_in[3];
  float* out = (float*)d_out;
  uint8_t* W = (uint8_t*)d_ws;

  unsigned* flags = (unsigned*)W;                                   // 3 x 64 flags
  unsigned short* hh  = (unsigned short*)(W + 0x10000);             // 3 x 32 x 64KB = 6MB
  unsigned short* Zin0 = (unsigned short*)(W + 0x800000);           // 128MB bf16 (B*T,4096)
  unsigned short* Xa  = (unsigned short*)(W + 0x8800000);           // 32MB bf16 (B*T,1024)
  unsigned short* WiT = (unsigned short*)(W + 0xA800000);           // 24MB bf16 (L,4096,1024)
  unsigned short* WhT = (unsigned short*)(W + 0xC000000);           // 24MB (ends 0xD800000)

  hipMemsetAsync(d_ws, 0, 4096, stream);                            // flags
  // zero slot HD-1 (=31) of each layer's h-ring (read as h(-1)=0 at t==0)
  hipMemsetAsync(W + 0x10000 + (size_t)31 * 65536, 0, 65536, stream);
  hipMemsetAsync(W + 0x10000 + (size_t)63 * 65536, 0, 65536, stream);
  hipMemsetAsync(W + 0x10000 + (size_t)95 * 65536, 0, 65536, stream);
  k_conv<<<8192, 256, 0, stream>>>(x, Xa, (B_ * T_ * D_) / 8);
  k_transw<<<dim3(32, 128, 3), 256, 0, stream>>>(Wi, WiT);
  k_transw<<<dim3(32, 128, 3), 256, 0, stream>>>(Wh, WhT);
  k_gemm_in<<<4096, 256, 0, stream>>>(Xa, WiT, Zin0);   // layer 0 input gates

  float* yout = out;
  float* hT = out + 16777216;
  float* cT = out + 16777216 + 98304;
  k_rec3<<<NWG3, 512, 65536, stream>>>(WiT, WhT, Zin0, bias, hh, flags, yout, hT, cT);
}

// Round 13
// 3138.230 us; speedup vs baseline: 1.2952x; 1.2952x over previous
//
#include <hip/hip_runtime.h>
#include <hip/hip_bf16.h>
#include <stdint.h>

typedef __bf16 bf16x8 __attribute__((ext_vector_type(8)));
typedef float f32x4 __attribute__((ext_vector_type(4)));
typedef short short8 __attribute__((ext_vector_type(8)));
typedef unsigned long long u64;
typedef unsigned int u32;

#define B_ 32
#define T_ 512
#define D_ 1024
#define NG 4096
#define L_ 3
#define HD 32            // rotating h step-buffer depth
#define HSLOT 32768      // ushorts per slot (32 batches x 1024 units)
#define NSTEP 514

__device__ inline unsigned short f2bf(float f) {
  unsigned u = __float_as_uint(f);
  unsigned r = (u + 0x7fffu + ((u >> 16) & 1u)) >> 16;
  return (unsigned short)r;
}
__device__ inline float bf2f(unsigned short h) {
  return __uint_as_float(((unsigned)h) << 16);
}
__device__ __forceinline__ float sigm(float x) { return 1.f / (1.f + __expf(-x)); }
__device__ __forceinline__ float tanh_(float x) {
  float e2 = __expf(-2.f * fabsf(x));
  return copysignf((1.f - e2) / (1.f + e2), x);
}

// ---------------- f32 -> bf16 convert (vectorized) ----------------
__global__ __launch_bounds__(256) void k_conv(const float* __restrict__ in,
                                              unsigned short* __restrict__ out, int n8) {
  int i = blockIdx.x * 256 + threadIdx.x;
  if (i >= n8) return;
  const float4* p = (const float4*)(in) + (size_t)i * 2;
  float4 a = p[0], b = p[1];
  short8 o;
  o[0] = (short)f2bf(a.x); o[1] = (short)f2bf(a.y); o[2] = (short)f2bf(a.z); o[3] = (short)f2bf(a.w);
  o[4] = (short)f2bf(b.x); o[5] = (short)f2bf(b.y); o[6] = (short)f2bf(b.z); o[7] = (short)f2bf(b.w);
  *((short8*)out + i) = o;
}

// ---------------- transpose+convert weights: (L,K,N) f32 -> (L,N,K) bf16 ----------------
__global__ __launch_bounds__(256) void k_transw(const float* __restrict__ in,
                                                unsigned short* __restrict__ out) {
  __shared__ float Tt[32][33];
  int k0 = blockIdx.x * 32, n0 = blockIdx.y * 32, l = blockIdx.z;
  const float* ip = in + (size_t)l * D_ * NG;
  unsigned short* op = out + (size_t)l * NG * D_;
  int r = threadIdx.x >> 5, c = threadIdx.x & 31;
  for (int rr = r; rr < 32; rr += 8)
    Tt[rr][c] = ip[(size_t)(k0 + rr) * NG + n0 + c];
  __syncthreads();
  for (int rr = r; rr < 32; rr += 8)
    op[(size_t)(n0 + rr) * D_ + k0 + c] = f2bf(Tt[c][rr]);
}

// ---------------- input-path GEMM (layer 0 only): Z = X @ Wi0 ----------------
#define PAD 40
__global__ __launch_bounds__(256) void k_gemm_in(const unsigned short* __restrict__ X,
                                                 const unsigned short* __restrict__ WT,
                                                 unsigned short* __restrict__ Z) {
  __shared__ short Al[128 * PAD];
  __shared__ short Bl[128 * PAD];
  int bx = blockIdx.x;
  int m0 = (bx >> 5) * 128, n0 = (bx & 31) * 128;
  int tid = threadIdx.x, lane = tid & 63, wv = tid >> 6;
  int wm = (wv >> 1) * 64, wn = (wv & 1) * 64;
  int l15 = lane & 15, lh = lane >> 4;
  f32x4 acc[4][4] = {};
  for (int s = 0; s < 32; ++s) {
    int k0 = s * 32;
    __syncthreads();
    for (int rr = 0; rr < 2; ++rr) {
      int ch = rr * 256 + tid;
      int row = ch >> 2, ko = (ch & 3) * 8;
      *(short8*)&Al[row * PAD + ko] = *(const short8*)&X[(size_t)(m0 + row) * 1024 + k0 + ko];
      *(short8*)&Bl[row * PAD + ko] = *(const short8*)&WT[(size_t)(n0 + row) * 1024 + k0 + ko];
    }
    __syncthreads();
    bf16x8 af[4], bfr[4];
    for (int mi = 0; mi < 4; ++mi)
      af[mi] = *(const bf16x8*)&Al[(wm + mi * 16 + l15) * PAD + lh * 8];
    for (int ni = 0; ni < 4; ++ni)
      bfr[ni] = *(const bf16x8*)&Bl[(wn + ni * 16 + l15) * PAD + lh * 8];
    for (int mi = 0; mi < 4; ++mi)
      for (int ni = 0; ni < 4; ++ni)
        acc[mi][ni] = __builtin_amdgcn_mfma_f32_16x16x32_bf16(af[mi], bfr[ni], acc[mi][ni], 0, 0, 0);
  }
  for (int mi = 0; mi < 4; ++mi)
    for (int ni = 0; ni < 4; ++ni)
      for (int r2 = 0; r2 < 4; ++r2) {
        int row = m0 + wm + mi * 16 + (lane >> 4) * 4 + r2;
        int col = n0 + wn + ni * 16 + l15;
        Z[(size_t)row * NG + col] = f2bf(acc[mi][ni][r2]);
      }
}

// ---------------- fused wavefronted 3-layer persistent recurrent kernel ----------------
// Round-13: byte-identical protocol to round 7 (best known). Only change: XCD-packed
// layer mapping. Grid=256; role=bid&7 maps to XCD via the round-robin dispatch
// heuristic; layer = role>>1 (so each layer's 64 WGs sit on exactly 2 XCDs, 1 WG/CU);
// roles 6,7 exit immediately. Correctness is mapping-independent (flags/rings are
// MALL-coherent); the mapping only concentrates L2 fills: each h slot now fills
// 2 L2s (own) + 2 (consumer) instead of 8+8 -> ~3x less MALL fill traffic per step.
template<int LAY>
__device__ __forceinline__ void rec_body(
    const unsigned short* __restrict__ WiL, const unsigned short* __restrict__ WhL,
    const unsigned short* __restrict__ Zin0, const float* __restrict__ biasL,
    unsigned short* __restrict__ hh, unsigned int* __restrict__ flags,
    float* __restrict__ yout, float* __restrict__ hT, float* __restrict__ cT,
    int wgl, float* zsb) {
  int tid = threadIdx.x, lane = tid & 63, kw = tid >> 6;
  int l15 = lane & 15, lh = lane >> 4;
  int U = wgl * 16;
  constexpr int NKF = (LAY == 0) ? 4 : 8;   // K-frags per wave (kspan = NKF*32)

  // ---- load this wave's weight B-fragments (register-resident) ----
  bf16x8 bw[4 * NKF];
  {
    const unsigned short* Wsrc;
    int k0;
    if (LAY == 0) { Wsrc = WhL; k0 = kw * 128; }
    else { Wsrc = (kw < 4) ? WiL : WhL; k0 = (kw & 3) * 256; }
#pragma unroll
    for (int nt = 0; nt < 4; ++nt)
#pragma unroll
      for (int kf = 0; kf < NKF; ++kf)
        bw[nt * NKF + kf] =
            *(const bf16x8*)&Wsrc[(size_t)(nt * 1024 + U + l15) * 1024 + k0 + kf * 32 + lh * 8];
  }
#pragma unroll
  for (int i = 0; i < 4 * NKF; ++i) asm volatile("" : "+v"(bw[i]));

  // elementwise cell: thread -> (batch b, unit j)
  int b = tid >> 4, j = tid & 15;
  int u = U + j;
  float bz0 = biasL[u], bz1 = biasL[1024 + u], bz2 = biasL[2048 + u], bz3 = biasL[3072 + u];
  float cst = 0.f;
  unsigned short* hhme = hh + (size_t)LAY * HD * HSLOT;
  const unsigned short* hhin = (LAY == 0) ? hhme : hh + (size_t)(LAY - 1) * HD * HSLOT;

  for (int s = 0; s < NSTEP; ++s) {
    int t = s - LAY;
    bool active = (t >= 0) && (t < T_);
    // ---- Zin prefetch (layer 0 only; overlaps the flag poll) ----
    unsigned short zv0 = 0, zv1 = 0, zv2 = 0, zv3 = 0;
    if (LAY == 0 && active) {
      const unsigned short* zr = Zin0 + (size_t)(b * T_ + t) * NG + u;
      zv0 = zr[0]; zv1 = zr[1024]; zv2 = zr[2048]; zv3 = zr[3072];
    }
    // ---- per-layer dependency wait (round-7 protocol, verbatim) ----
    if (s > 0) {
      if (kw == 0) {
        unsigned ss = (unsigned)s;
        const u32* fown = flags + LAY * 64 + lane;
        bool bp_on = (LAY < 2) && (s >= 32);
        unsigned bp = bp_on ? (unsigned)(s - 24) : 0u;
        for (;;) {
          bool ok = __hip_atomic_load(fown, __ATOMIC_RELAXED, __HIP_MEMORY_SCOPE_AGENT) >= ss;
          if constexpr (LAY > 0)
            ok &= __hip_atomic_load(flags + (LAY - 1) * 64 + lane, __ATOMIC_RELAXED,
                                    __HIP_MEMORY_SCOPE_AGENT) >= ss;
          if constexpr (LAY < 2) {
            if (bp_on)
              ok &= __hip_atomic_load(flags + (LAY + 1) * 64 + lane, __ATOMIC_RELAXED,
                                      __HIP_MEMORY_SCOPE_AGENT) >= bp;
          }
          if (__all(ok)) break;
          __builtin_amdgcn_s_sleep(1);
        }
        if ((s & (HD - 1)) == 0)
          __builtin_amdgcn_fence(__ATOMIC_ACQUIRE, "agent");  // ring-reuse freshness
      }
      __syncthreads();
    }
    if (active) {
      // ---- GEMM: this wave's K-slice (unconditional; slot HD-1 zeroed for t==0) ----
      const unsigned short* hsrc;
      if (LAY == 0)      hsrc = hhme + (size_t)((t - 1) & (HD - 1)) * HSLOT;
      else if (kw < 4)   hsrc = hhin + (size_t)(t & (HD - 1)) * HSLOT;
      else               hsrc = hhme + (size_t)((t - 1) & (HD - 1)) * HSLOT;
      f32x4 acc[2][4] = {};
#pragma unroll
      for (int kf = 0; kf < NKF; ++kf) {
        int k = (LAY == 0 ? kw * 128 : (kw & 3) * 256) + kf * 32 + lh * 8;
        const unsigned short* pa = hsrc + (k >> 2) * 128;
        u64 x0 = *(const u64*)(pa + l15 * 4);
        u64 x1 = *(const u64*)(pa + 128 + l15 * 4);
        u64 x2 = *(const u64*)(pa + 64 + l15 * 4);
        u64 x3 = *(const u64*)(pa + 192 + l15 * 4);
        bf16x8 a0, a1;
        ((u64*)&a0)[0] = x0; ((u64*)&a0)[1] = x1;
        ((u64*)&a1)[0] = x2; ((u64*)&a1)[1] = x3;
#pragma unroll
        for (int nt = 0; nt < 4; ++nt) {
          acc[0][nt] = __builtin_amdgcn_mfma_f32_16x16x32_bf16(a0, bw[nt * NKF + kf], acc[0][nt], 0, 0, 0);
          acc[1][nt] = __builtin_amdgcn_mfma_f32_16x16x32_bf16(a1, bw[nt * NKF + kf], acc[1][nt], 0, 0, 0);
        }
      }
      // ---- write split-K partials: zs[kw][mt*4+nt][lane][4] ----
#pragma unroll
      for (int mt = 0; mt < 2; ++mt)
#pragma unroll
        for (int nt = 0; nt < 4; ++nt)
          *(f32x4*)&zsb[(((kw * 8) + mt * 4 + nt) * 64 + lane) * 4] = acc[mt][nt];
    }
    __syncthreads();
    float hv = 0.f;   // kept for post-flag stores
    if (active) {
      // ---- reduce 8 partials + gates + state update ----
      int mt = b >> 4, lzs = ((b & 15) >> 2) * 16 + j, r = b & 3;
      float z0 = bz0, z1 = bz1, z2 = bz2, z3 = bz3;
#pragma unroll
      for (int k2 = 0; k2 < 8; ++k2) {
        int base = ((k2 * 8 + mt * 4) * 64 + lzs) * 4 + r;
        z0 += zsb[base];
        z1 += zsb[base + 256];
        z2 += zsb[base + 512];
        z3 += zsb[base + 768];
      }
      if (LAY == 0) { z0 += bf2f(zv0); z1 += bf2f(zv1); z2 += bf2f(zv2); z3 += bf2f(zv3); }
      float ig = sigm(z0), fg = sigm(z1), gg = tanh_(z2), og = sigm(z3);
      cst = fg * cst + ig * gg;
      hv = og * tanh_(cst);
      unsigned short hw = f2bf(hv);
      unsigned short* ha = hhme + (size_t)(t & (HD - 1)) * HSLOT + (u >> 2) * 128 + b * 4 + (u & 3);
      unsigned hw32 = hw;
      asm volatile("global_store_short %0, %1, off sc0 sc1" :: "v"(ha), "v"(hw32) : "memory");
    }
    // drain h-stores only (output stores are issued after the flag)
    asm volatile("s_waitcnt vmcnt(0)" ::: "memory");
    __syncthreads();
    if (tid == 0 && s < NSTEP - 1)
      __hip_atomic_store(&flags[LAY * 64 + wgl], (unsigned)(s + 1), __ATOMIC_RELAXED,
                         __HIP_MEMORY_SCOPE_AGENT);
    // ---- off-critical-path output stores ----
    if (active) {
      if (LAY == 2) __builtin_nontemporal_store(hv, &yout[(size_t)(b * T_ + t) * 1024 + u]);
      if (t == T_ - 1) {
        hT[LAY * (B_ * 1024) + b * 1024 + u] = hv;
        cT[LAY * (B_ * 1024) + b * 1024 + u] = cst;
      }
    }
  }
}

__global__ __launch_bounds__(512)
__attribute__((amdgpu_waves_per_eu(2, 2)))
void k_rec3(
    const unsigned short* __restrict__ WiT, const unsigned short* __restrict__ WhT,
    const unsigned short* __restrict__ Zin0, const float* __restrict__ bias,
    unsigned short* __restrict__ hh, unsigned int* __restrict__ flags,
    float* __restrict__ yout, float* __restrict__ hT, float* __restrict__ cT) {
  extern __shared__ float zsb[];   // 64KB: [kw][8][64][4] f32
  int bid = blockIdx.x;
  int role = bid & 7;              // dispatch round-robin: role == XCD (heuristic)
  int lay = role >> 1;             // XCDs {0,1}->L0, {2,3}->L1, {4,5}->L2
  if (lay > 2) return;             // XCDs 6,7 idle
  int wgl = ((role & 1) << 5) + (bid >> 3);   // 0..63 within layer
  const unsigned short* WiL = WiT + (size_t)lay * NG * 1024;
  const unsigned short* WhL = WhT + (size_t)lay * NG * 1024;
  const float* biasL = bias + lay * NG;
  if (lay == 0)      rec_body<0>(WiL, WhL, Zin0, biasL, hh, flags, yout, hT, cT, wgl, zsb);
  else if (lay == 1) rec_body<1>(WiL, WhL, Zin0, biasL, hh, flags, yout, hT, cT, wgl, zsb);
  else               rec_body<2>(WiL, WhL, Zin0, biasL, hh, flags, yout, hT, cT, wgl, zsb);
}

extern "C" void kernel_launch(void* const* d_in, const int* in_sizes, int n_in,
                              void* d_out, int out_size, void* d_ws, size_t ws_size,
                              hipStream_t stream) {
  const float* x = (const float*)d_in[0];
  const float* Wi = (const float*)d_in[1];
  const float* Wh = (const float*)d_in[2];
  const float* bias = (const float*)d_in[3];
  float* out = (float*)d_out;
  uint8_t* W = (uint8_t*)d_ws;

  unsigned* flags = (unsigned*)W;                                   // 3 x 64 flags
  unsigned short* hh  = (unsigned short*)(W + 0x10000);             // 3 x 32 x 64KB = 6MB
  unsigned short* Zin0 = (unsigned short*)(W + 0x800000);           // 128MB bf16 (B*T,4096)
  unsigned short* Xa  = (unsigned short*)(W + 0x8800000);           // 32MB bf16 (B*T,1024)
  unsigned short* WiT = (unsigned short*)(W + 0xA800000);           // 24MB bf16 (L,4096,1024)
  unsigned short* WhT = (unsigned short*)(W + 0xC000000);           // 24MB (ends 0xD800000)

  hipMemsetAsync(d_ws, 0, 4096, stream);                            // flags
  // zero slot HD-1 (=31) of each layer's h-ring (read as h(-1)=0 at t==0)
  hipMemsetAsync(W + 0x10000 + (size_t)31 * 65536, 0, 65536, stream);
  hipMemsetAsync(W + 0x10000 + (size_t)63 * 65536, 0, 65536, stream);
  hipMemsetAsync(W + 0x10000 + (size_t)95 * 65536, 0, 65536, stream);
  k_conv<<<8192, 256, 0, stream>>>(x, Xa, (B_ * T_ * D_) / 8);
  k_transw<<<dim3(32, 128, 3), 256, 0, stream>>>(Wi, WiT);
  k_transw<<<dim3(32, 128, 3), 256, 0, stream>>>(Wh, WhT);
  k_gemm_in<<<4096, 256, 0, stream>>>(Xa, WiT, Zin0);   // layer 0 input gates

  float* yout = out;
  float* hT = out + 16777216;
  float* cT = out + 16777216 + 98304;
  k_rec3<<<256, 512, 65536, stream>>>(WiT, WhT, Zin0, bias, hh, flags, yout, hT, cT);
}

// Round 14
// 2580.672 us; speedup vs baseline: 1.5751x; 1.2161x over previous
//
#include <hip/hip_runtime.h>
#include <hip/hip_bf16.h>
#include <stdint.h>

typedef __bf16 bf16x8 __attribute__((ext_vector_type(8)));
typedef float f32x4 __attribute__((ext_vector_type(4)));
typedef short short8 __attribute__((ext_vector_type(8)));
typedef unsigned long long u64;
typedef unsigned int u32;

#define B_ 32
#define T_ 512
#define D_ 1024
#define NG 4096
#define HD 32            // all rings 32-deep (= fence cadence)
#define HSLOT 32768      // ushorts per h slot
#define ZSLOT 131072     // ushorts per zin slot (4 gates x 32768)

__device__ inline unsigned short f2bf(float f) {
  unsigned u = __float_as_uint(f);
  unsigned r = (u + 0x7fffu + ((u >> 16) & 1u)) >> 16;
  return (unsigned short)r;
}
__device__ inline float bf2f(unsigned short h) {
  return __uint_as_float(((unsigned)h) << 16);
}
__device__ __forceinline__ float sigm(float x) { return 1.f / (1.f + __expf(-x)); }
__device__ __forceinline__ float tanh_(float x) {
  float e2 = __expf(-2.f * fabsf(x));
  return copysignf((1.f - e2) / (1.f + e2), x);
}
__device__ __forceinline__ u32 ld_mall(const u32* p) {
  return __hip_atomic_load(p, __ATOMIC_RELAXED, __HIP_MEMORY_SCOPE_AGENT);
}

// ---------------- f32 -> bf16 convert (vectorized) ----------------
__global__ __launch_bounds__(256) void k_conv(const float* __restrict__ in,
                                              unsigned short* __restrict__ out, int n8) {
  int i = blockIdx.x * 256 + threadIdx.x;
  if (i >= n8) return;
  const float4* p = (const float4*)(in) + (size_t)i * 2;
  float4 a = p[0], b = p[1];
  short8 o;
  o[0] = (short)f2bf(a.x); o[1] = (short)f2bf(a.y); o[2] = (short)f2bf(a.z); o[3] = (short)f2bf(a.w);
  o[4] = (short)f2bf(b.x); o[5] = (short)f2bf(b.y); o[6] = (short)f2bf(b.z); o[7] = (short)f2bf(b.w);
  *((short8*)out + i) = o;
}

// ---------------- transpose+convert weights: (L,K,N) f32 -> (L,N,K) bf16 ----------------
__global__ __launch_bounds__(256) void k_transw(const float* __restrict__ in,
                                                unsigned short* __restrict__ out) {
  __shared__ float Tt[32][33];
  int k0 = blockIdx.x * 32, n0 = blockIdx.y * 32, l = blockIdx.z;
  const float* ip = in + (size_t)l * D_ * NG;
  unsigned short* op = out + (size_t)l * NG * D_;
  int r = threadIdx.x >> 5, c = threadIdx.x & 31;
  for (int rr = r; rr < 32; rr += 8)
    Tt[rr][c] = ip[(size_t)(k0 + rr) * NG + n0 + c];
  __syncthreads();
  for (int rr = r; rr < 32; rr += 8)
    op[(size_t)(n0 + rr) * D_ + k0 + c] = f2bf(Tt[c][rr]);
}

// ---------------- input-path GEMM (layer 0 only): Z = X @ Wi0 ----------------
#define PAD 40
__global__ __launch_bounds__(256) void k_gemm_in(const unsigned short* __restrict__ X,
                                                 const unsigned short* __restrict__ WT,
                                                 unsigned short* __restrict__ Z) {
  __shared__ short Al[128 * PAD];
  __shared__ short Bl[128 * PAD];
  int bx = blockIdx.x;
  int m0 = (bx >> 5) * 128, n0 = (bx & 31) * 128;
  int tid = threadIdx.x, lane = tid & 63, wv = tid >> 6;
  int wm = (wv >> 1) * 64, wn = (wv & 1) * 64;
  int l15 = lane & 15, lh = lane >> 4;
  f32x4 acc[4][4] = {};
  for (int s = 0; s < 32; ++s) {
    int k0 = s * 32;
    __syncthreads();
    for (int rr = 0; rr < 2; ++rr) {
      int ch = rr * 256 + tid;
      int row = ch >> 2, ko = (ch & 3) * 8;
      *(short8*)&Al[row * PAD + ko] = *(const short8*)&X[(size_t)(m0 + row) * 1024 + k0 + ko];
      *(short8*)&Bl[row * PAD + ko] = *(const short8*)&WT[(size_t)(n0 + row) * 1024 + k0 + ko];
    }
    __syncthreads();
    bf16x8 af[4], bfr[4];
    for (int mi = 0; mi < 4; ++mi)
      af[mi] = *(const bf16x8*)&Al[(wm + mi * 16 + l15) * PAD + lh * 8];
    for (int ni = 0; ni < 4; ++ni)
      bfr[ni] = *(const bf16x8*)&Bl[(wn + ni * 16 + l15) * PAD + lh * 8];
    for (int mi = 0; mi < 4; ++mi)
      for (int ni = 0; ni < 4; ++ni)
        acc[mi][ni] = __builtin_amdgcn_mfma_f32_16x16x32_bf16(af[mi], bfr[ni], acc[mi][ni], 0, 0, 0);
  }
  for (int mi = 0; mi < 4; ++mi)
    for (int ni = 0; ni < 4; ++ni)
      for (int r2 = 0; r2 < 4; ++r2) {
        int row = m0 + wm + mi * 16 + (lane >> 4) * 4 + r2;
        int col = n0 + wn + ni * 16 + l15;
        Z[(size_t)row * NG + col] = f2bf(acc[mi][ni][r2]);
      }
}

// ================== rec body: 64 WGs/layer (2 XCDs), K=1024 own-h only ==================
// All layers now LAY0-shaped: x contribution comes from Zin0 (LAY0, static) or the
// zin ring written by the inGEMM WGs (LAY>0). Transport/protocol = proven r13.
template<int LAY>
__device__ __forceinline__ void rec_body(
    const unsigned short* __restrict__ WhL, const unsigned short* __restrict__ Zin0,
    const float* __restrict__ biasL, unsigned short* __restrict__ hh,
    const unsigned short* __restrict__ zring,  // this layer's zin ring (LAY>0)
    u32* __restrict__ recF, u32* __restrict__ ingF,
    float* __restrict__ yout, float* __restrict__ hT, float* __restrict__ cT,
    int wgl, float* zsb) {
  int tid = threadIdx.x, lane = tid & 63, kw = tid >> 6;
  int l15 = lane & 15, lh = lane >> 4;
  int U = wgl * 16;

  // weights: Wh slice, 16 frags (64 VGPRs)
  bf16x8 bw[16];
#pragma unroll
  for (int nt = 0; nt < 4; ++nt)
#pragma unroll
    for (int kf = 0; kf < 4; ++kf)
      bw[nt * 4 + kf] =
          *(const bf16x8*)&WhL[(size_t)(nt * 1024 + U + l15) * 1024 + kw * 128 + kf * 32 + lh * 8];
#pragma unroll
  for (int i = 0; i < 16; ++i) asm volatile("" : "+v"(bw[i]));

  int b = tid >> 4, j = tid & 15;
  int u = U + j;
  float bz0 = biasL[u], bz1 = biasL[1024 + u], bz2 = biasL[2048 + u], bz3 = biasL[3072 + u];
  float cst = 0.f;
  unsigned short* hhme = hh + (size_t)LAY * HD * HSLOT;
  const u32* fup = (LAY > 0) ? ingF + (LAY - 1) * 32 + (wgl >> 1) : nullptr;

  for (int t = 0; t < T_; ++t) {
    // Zin0 prefetch (LAY0; static buffer, overlaps poll)
    unsigned short zv0 = 0, zv1 = 0, zv2 = 0, zv3 = 0;
    if (LAY == 0) {
      const unsigned short* zr = Zin0 + (size_t)(b * T_ + t) * NG + u;
      zv0 = zr[0]; zv1 = zr[1024]; zv2 = zr[2048]; zv3 = zr[3072];
    }
    // ---- polls (wave 0): own 64 flags >= t; upstream inG flag >= t+1 ----
    if (kw == 0) {
      if (t > 0 || LAY > 0) {
        const u32* fown = recF + LAY * 64 + lane;
        for (;;) {
          bool ok = true;
          if (t > 0) ok = ld_mall(fown) >= (u32)t;
          if (LAY > 0) ok &= ld_mall(fup) >= (u32)(t + 1);
          if (__all(ok)) break;
          __builtin_amdgcn_s_sleep(1);
        }
      }
      // backpressure: inG(LAY+1) reads my h ring; keep it within 24 steps
      if (LAY < 2 && t >= 32 && (t & 7) == 0) {
        const u32* fd = ingF + LAY * 32 + (lane & 31);
        u32 need = (u32)(t - 24);
        for (;;) {
          u32 f = ld_mall(fd);
          if (__all((lane >= 32) || (f >= need))) break;
          __builtin_amdgcn_s_sleep(1);
        }
      }
      if (t > 0 && (t & 31) == 0)
        __builtin_amdgcn_fence(__ATOMIC_ACQUIRE, "agent");  // ring-reuse freshness
    }
    __syncthreads();
    // zin ring read (LAY>0; valid after join)
    unsigned short zq0 = 0, zq1 = 0, zq2 = 0, zq3 = 0;
    if (LAY > 0) {
      const unsigned short* zs = zring + (size_t)(t & (HD - 1)) * ZSLOT +
                                 (u >> 2) * 128 + b * 4 + (u & 3);
      zq0 = zs[0]; zq1 = zs[32768]; zq2 = zs[65536]; zq3 = zs[98304];
    }
    // ---- recurrent GEMM: own h(t-1), K=1024 (slot 31 zeroed for t==0) ----
    {
      const unsigned short* hsrc = hhme + (size_t)((t - 1) & (HD - 1)) * HSLOT;
      f32x4 acc[2][4] = {};
#pragma unroll
      for (int kf = 0; kf < 4; ++kf) {
        int k = kw * 128 + kf * 32 + lh * 8;
        const unsigned short* pa = hsrc + (k >> 2) * 128;
        u64 x0 = *(const u64*)(pa + l15 * 4);
        u64 x1 = *(const u64*)(pa + 128 + l15 * 4);
        u64 x2 = *(const u64*)(pa + 64 + l15 * 4);
        u64 x3 = *(const u64*)(pa + 192 + l15 * 4);
        bf16x8 a0, a1;
        ((u64*)&a0)[0] = x0; ((u64*)&a0)[1] = x1;
        ((u64*)&a1)[0] = x2; ((u64*)&a1)[1] = x3;
#pragma unroll
        for (int nt = 0; nt < 4; ++nt) {
          acc[0][nt] = __builtin_amdgcn_mfma_f32_16x16x32_bf16(a0, bw[nt * 4 + kf], acc[0][nt], 0, 0, 0);
          acc[1][nt] = __builtin_amdgcn_mfma_f32_16x16x32_bf16(a1, bw[nt * 4 + kf], acc[1][nt], 0, 0, 0);
        }
      }
#pragma unroll
      for (int mt = 0; mt < 2; ++mt)
#pragma unroll
        for (int nt = 0; nt < 4; ++nt)
          *(f32x4*)&zsb[(((kw * 8) + mt * 4 + nt) * 64 + lane) * 4] = acc[mt][nt];
    }
    __syncthreads();
    // ---- reduce 8 K-partials + gates + state update ----
    float hv;
    {
      int mt = b >> 4, lzs = ((b & 15) >> 2) * 16 + j, r = b & 3;
      float z0 = bz0, z1 = bz1, z2 = bz2, z3 = bz3;
#pragma unroll
      for (int k2 = 0; k2 < 8; ++k2) {
        int base = ((k2 * 8 + mt * 4) * 64 + lzs) * 4 + r;
        z0 += zsb[base];
        z1 += zsb[base + 256];
        z2 += zsb[base + 512];
        z3 += zsb[base + 768];
      }
      if (LAY == 0) { z0 += bf2f(zv0); z1 += bf2f(zv1); z2 += bf2f(zv2); z3 += bf2f(zv3); }
      else          { z0 += bf2f(zq0); z1 += bf2f(zq1); z2 += bf2f(zq2); z3 += bf2f(zq3); }
      float ig = sigm(z0), fg = sigm(z1), gg = tanh_(z2), og = sigm(z3);
      cst = fg * cst + ig * gg;
      hv = og * tanh_(cst);
      unsigned short hw = f2bf(hv);
      unsigned short* ha = hhme + (size_t)(t & (HD - 1)) * HSLOT + (u >> 2) * 128 + b * 4 + (u & 3);
      unsigned hw32 = hw;
      asm volatile("global_store_short %0, %1, off sc0 sc1" :: "v"(ha), "v"(hw32) : "memory");
    }
    asm volatile("s_waitcnt vmcnt(0)" ::: "memory");
    __syncthreads();
    if (tid == 0)
      __hip_atomic_store(&recF[LAY * 64 + wgl], (u32)(t + 1), __ATOMIC_RELAXED,
                         __HIP_MEMORY_SCOPE_AGENT);
    // off-critical-path outputs
    if (LAY == 2) __builtin_nontemporal_store(hv, &yout[(size_t)(b * T_ + t) * 1024 + u]);
    if (t == T_ - 1) {
      hT[LAY * (B_ * 1024) + b * 1024 + u] = hv;
      cT[LAY * (B_ * 1024) + b * 1024 + u] = cst;
    }
  }
}

// ================== inGEMM body: Zin_lc(t) = h_{lc-1}(t) @ Wi_lc ==================
// 32 WGs per consumer layer (lc = 1,2) on XCDs 6,7. Each WG owns 32 units (128 z-cols).
// 8 waves = 4 K-spans(256) x 2 N-halves(64 cols). Writes bf16 to 32-deep MALL zin ring.
template<int LC>
__device__ __forceinline__ void ing_body(
    const unsigned short* __restrict__ WiL, unsigned short* __restrict__ hh,
    unsigned short* __restrict__ zring, u32* __restrict__ recF, u32* __restrict__ ingF,
    int w, float* zsb) {
  int tid = threadIdx.x, lane = tid & 63, wv = tid >> 6;
  int l15 = lane & 15, lh = lane >> 4;
  int kw = wv & 3, nh = wv >> 2;

  // weights: Wi slice, 32 frags (128 VGPRs)
  bf16x8 bw[32];
#pragma unroll
  for (int nt = 0; nt < 4; ++nt) {
    int c = nh * 64 + nt * 16 + l15;
    int row = (c >> 5) * 1024 + w * 32 + (c & 31);
#pragma unroll
    for (int kf = 0; kf < 8; ++kf)
      bw[nt * 8 + kf] = *(const bf16x8*)&WiL[(size_t)row * 1024 + kw * 256 + kf * 32 + lh * 8];
  }
#pragma unroll
  for (int i = 0; i < 32; ++i) asm volatile("" : "+v"(bw[i]));

  int b = tid >> 4, j2 = (tid & 15) * 2;
  const unsigned short* hin = hh + (size_t)(LC - 1) * HD * HSLOT;
  int mt = b >> 4, lh2 = (b & 15) >> 2, r = b & 3;

  for (int t = 0; t < T_; ++t) {
    // ---- polls (wave 0): upstream rec 64 flags >= t+1; bp on consumer rec(LC) ----
    if (wv == 0) {
      const u32* fup = recF + (LC - 1) * 64 + lane;
      for (;;) {
        u32 f = ld_mall(fup);
        if (__all(f >= (u32)(t + 1))) break;
        __builtin_amdgcn_s_sleep(1);
      }
      if (t >= 32 && (t & 7) == 0) {
        const u32* fc = recF + LC * 64 + lane;
        u32 need = (u32)(t - 24);
        for (;;) {
          u32 f = ld_mall(fc);
          if (__all(f >= need)) break;
          __builtin_amdgcn_s_sleep(1);
        }
      }
      if (t > 0 && (t & 31) == 0)
        __builtin_amdgcn_fence(__ATOMIC_ACQUIRE, "agent");
    }
    __syncthreads();
    // ---- GEMM: h_{lc-1}(t) @ Wi, this wave's (K-span, N-half) ----
    {
      const unsigned short* base = hin + (size_t)(t & (HD - 1)) * HSLOT;
      f32x4 acc[2][4] = {};
#pragma unroll
      for (int kf = 0; kf < 8; ++kf) {
        int k = kw * 256 + kf * 32 + lh * 8;
        const unsigned short* pa = base + (k >> 2) * 128;
        u64 x0 = *(const u64*)(pa + l15 * 4);
        u64 x1 = *(const u64*)(pa + 128 + l15 * 4);
        u64 x2 = *(const u64*)(pa + 64 + l15 * 4);
        u64 x3 = *(const u64*)(pa + 192 + l15 * 4);
        bf16x8 a0, a1;
        ((u64*)&a0)[0] = x0; ((u64*)&a0)[1] = x1;
        ((u64*)&a1)[0] = x2; ((u64*)&a1)[1] = x3;
#pragma unroll
        for (int nt = 0; nt < 4; ++nt) {
          acc[0][nt] = __builtin_amdgcn_mfma_f32_16x16x32_bf16(a0, bw[nt * 8 + kf], acc[0][nt], 0, 0, 0);
          acc[1][nt] = __builtin_amdgcn_mfma_f32_16x16x32_bf16(a1, bw[nt * 8 + kf], acc[1][nt], 0, 0, 0);
        }
      }
      // partials: row = (kw*2+mt)*8 + (nh*4+nt)
#pragma unroll
      for (int mtq = 0; mtq < 2; ++mtq)
#pragma unroll
        for (int nt = 0; nt < 4; ++nt)
          *(f32x4*)&zsb[(((kw * 2 + mtq) * 8) + nh * 4 + nt) * 256 + lane * 4] = acc[mtq][nt];
    }
    __syncthreads();
    // ---- reduce 4 K-partials; write bf16 pairs to zin ring (write-through) ----
    {
      unsigned short* zslot = zring + (size_t)(t & (HD - 1)) * ZSLOT;
      int u0 = w * 32 + j2;
#pragma unroll
      for (int g = 0; g < 4; ++g) {
        float zz[2];
#pragma unroll
        for (int cell = 0; cell < 2; ++cell) {
          int c = g * 32 + j2 + cell;
          int ntg = c >> 4, l15c = c & 15;
          int idx = ((mt)*8 + ntg) * 256 + (lh2 * 16 + l15c) * 4 + r;
          float s = zsb[idx];
#pragma unroll
          for (int kq = 1; kq < 4; ++kq) s += zsb[idx + kq * 4096];
          zz[cell] = s;
        }
        u32 zd = (u32)f2bf(zz[0]) | ((u32)f2bf(zz[1]) << 16);
        unsigned short* za = zslot + g * 32768 + (u0 >> 2) * 128 + b * 4 + (u0 & 3);
        asm volatile("global_store_dword %0, %1, off sc0 sc1" :: "v"(za), "v"(zd) : "memory");
      }
    }
    asm volatile("s_waitcnt vmcnt(0)" ::: "memory");
    __syncthreads();
    if (tid == 0)
      __hip_atomic_store(&ingF[(LC - 1) * 32 + w], (u32)(t + 1), __ATOMIC_RELAXED,
                         __HIP_MEMORY_SCOPE_AGENT);
  }
}

__global__ __launch_bounds__(512)
__attribute__((amdgpu_waves_per_eu(2, 2)))
void k_rec3(
    const unsigned short* __restrict__ WiT, const unsigned short* __restrict__ WhT,
    const unsigned short* __restrict__ Zin0, const float* __restrict__ bias,
    unsigned short* __restrict__ hh, unsigned short* __restrict__ zrings,
    u32* __restrict__ recF, u32* __restrict__ ingF,
    float* __restrict__ yout, float* __restrict__ hT, float* __restrict__ cT) {
  extern __shared__ float zsb[];   // 64KB
  int bid = blockIdx.x;
  int role = bid & 7;              // round-robin: role == XCD (heuristic; perf-only)
  if (role < 6) {
    int lay = role >> 1;           // XCDs {0,1}->L0, {2,3}->L1, {4,5}->L2
    int wgl = ((role & 1) << 5) + (bid >> 3);
    const unsigned short* WhL = WhT + (size_t)lay * NG * 1024;
    const float* biasL = bias + lay * NG;
    const unsigned short* zr = zrings + (size_t)(lay > 0 ? lay - 1 : 0) * HD * ZSLOT;
    if (lay == 0)
      rec_body<0>(WhL, Zin0, biasL, hh, zr, recF, ingF, yout, hT, cT, wgl, zsb);
    else if (lay == 1)
      rec_body<1>(WhL, Zin0, biasL, hh, zr, recF, ingF, yout, hT, cT, wgl, zsb);
    else
      rec_body<2>(WhL, Zin0, biasL, hh, zr, recF, ingF, yout, hT, cT, wgl, zsb);
  } else {
    int w = bid >> 3;              // 0..31
    if (role == 6)
      ing_body<1>(WiT + (size_t)1 * NG * 1024, hh, zrings, recF, ingF, w, zsb);
    else
      ing_body<2>(WiT + (size_t)2 * NG * 1024, hh, zrings + (size_t)HD * ZSLOT,
                  recF, ingF, w, zsb);
  }
}

extern "C" void kernel_launch(void* const* d_in, const int* in_sizes, int n_in,
                              void* d_out, int out_size, void* d_ws, size_t ws_size,
                              hipStream_t stream) {
  const float* x = (const float*)d_in[0];
  const float* Wi = (const float*)d_in[1];
  const float* Wh = (const float*)d_in[2];
  const float* bias = (const float*)d_in[3];
  float* out = (float*)d_out;
  uint8_t* W = (uint8_t*)d_ws;

  u32* recF = (u32*)W;                                              // 3 x 64 flags
  u32* ingF = (u32*)(W + 0x1000);                                   // 2 x 32 flags
  unsigned short* hh     = (unsigned short*)(W + 0x10000);          // 3 x 32 x 64KB = 6MB
  unsigned short* zrings = (unsigned short*)(W + 0x700000);         // 2 x 32 x 256KB = 16MB
  unsigned short* Zin0   = (unsigned short*)(W + 0x1700000);        // 128MB bf16 (B*T,4096)
  unsigned short* Xa     = (unsigned short*)(W + 0x9700000);        // 32MB bf16 (B*T,1024)
  unsigned short* WiT    = (unsigned short*)(W + 0xB700000);        // 24MB bf16 (L,4096,1024)
  unsigned short* WhT    = (unsigned short*)(W + 0xD300000);        // 24MB (ends 0xEB00000)

  hipMemsetAsync(W, 0, 0x2000, stream);                             // all flags
  // zero slot 31 of each layer's h-ring (read as h(-1)=0 at t==0)
  hipMemsetAsync(W + 0x10000 + (size_t)31 * 65536, 0, 65536, stream);
  hipMemsetAsync(W + 0x10000 + (size_t)63 * 65536, 0, 65536, stream);
  hipMemsetAsync(W + 0x10000 + (size_t)95 * 65536, 0, 65536, stream);
  k_conv<<<8192, 256, 0, stream>>>(x, Xa, (B_ * T_ * D_) / 8);
  k_transw<<<dim3(32, 128, 3), 256, 0, stream>>>(Wi, WiT);
  k_transw<<<dim3(32, 128, 3), 256, 0, stream>>>(Wh, WhT);
  k_gemm_in<<<4096, 256, 0, stream>>>(Xa, WiT, Zin0);   // layer 0 input gates

  float* yout = out;
  float* hT = out + 16777216;
  float* cT = out + 16777216 + 98304;
  k_rec3<<<256, 512, 65536, stream>>>(WiT, WhT, Zin0, bias, hh, zrings,
                                      recF, ingF, yout, hT, cT);
}